// Round 1
// 1387.315 us; speedup vs baseline: 1.1461x; 1.1461x over previous
//
#include <hip/hip_runtime.h>
#include <cstdio>
#include <cstdint>

typedef unsigned short u16;
typedef short short8 __attribute__((ext_vector_type(8)));
typedef float floatx4 __attribute__((ext_vector_type(4)));

#define NPIX 16384      // 128*128
#define DIM 256

__device__ inline float bf2f(u16 v) {
    return __uint_as_float(((uint32_t)v) << 16);
}
__device__ inline u16 f2bf(float f) {
    uint32_t u = __float_as_uint(f);
    u += 0x7fffu + ((u >> 16) & 1u);
    return (u16)(u >> 16);
}
__device__ inline float gelu_tanh(float x) {
    float x3 = x * x * x;
    return 0.5f * x * (1.f + tanhf(0.7978845608028654f * (x + 0.044715f * x3)));
}
// flag-aware load of 8 consecutive elements from a raw input tensor
__device__ inline void load8(const u16* p, size_t idx, int isf32, float out[8]) {
    if (isf32) {
        const float4* f = (const float4*)((const float*)p + idx);
        float4 a = f[0], b = f[1];
        out[0] = a.x; out[1] = a.y; out[2] = a.z; out[3] = a.w;
        out[4] = b.x; out[5] = b.y; out[6] = b.z; out[7] = b.w;
    } else {
        uint4 d = *(const uint4*)(p + idx);
        u16 v[8]; *(uint4*)v = d;
#pragma unroll
        for (int j = 0; j < 8; ++j) out[j] = bf2f(v[j]);
    }
}

// ---------------- dtype sniffer: low u16 of each word is a plausible bf16 only for bf16 data
__global__ __launch_bounds__(256)
void detect_dtype(const u16* __restrict__ x, int* __restrict__ flag) {
    __shared__ int sh[256];
    int t = threadIdx.x;
    const uint32_t* w = (const uint32_t*)x;
    int cnt = 0;
    for (int i = t; i < 4096; i += 256) {
        int e = (w[i] >> 7) & 0xFF;
        if (e >= 110 && e <= 134) cnt++;
    }
    sh[t] = cnt;
    __syncthreads();
    if (t == 0) {
        int s = 0;
        for (int i = 0; i < 256; ++i) s += sh[i];
        *flag = (s < 2048) ? 1 : 0;    // 1 => inputs are float32
    }
}

// ---------------- convert all parameter tensors to canonical bf16 in ws
struct WArgs {
    const void* src[17];
    int off[17];
    int n[17];
};
__global__ __launch_bounds__(256)
void convert_params(WArgs a, const int* __restrict__ flag, u16* __restrict__ dst) {
    int isf32 = *flag;
    int w = blockIdx.y;
    const void* s = a.src[w];
    u16* d = dst + a.off[w];
    int n = a.n[w];
    for (int i = blockIdx.x * 256 + threadIdx.x; i < n; i += gridDim.x * 256)
        d[i] = isf32 ? f2bf(((const float*)s)[i]) : ((const u16*)s)[i];
}

// ---------------- LN stats: per-pixel mean/rstd over 256 channels (NCHW input)
__global__ __launch_bounds__(256)
void ln_stats(const u16* __restrict__ x, const int* __restrict__ flag,
              float* __restrict__ mu, float* __restrict__ rstd) {
    int isf32 = *flag;
    int g = blockIdx.x * 256 + threadIdx.x;       // pixel id 0..131071
    int b = g >> 14, n = g & (NPIX - 1);
    float s = 0.f, s2 = 0.f;
    if (isf32) {
        const float* p = (const float*)x + (size_t)b * DIM * NPIX + n;
        for (int c = 0; c < DIM; ++c) { float v = p[(size_t)c * NPIX]; s += v; s2 += v * v; }
    } else {
        const u16* p = x + (size_t)b * DIM * NPIX + n;
        for (int c = 0; c < DIM; ++c) { float v = bf2f(p[(size_t)c * NPIX]); s += v; s2 += v * v; }
    }
    float m = s * (1.f / 256.f);
    float var = s2 * (1.f / 256.f) - m * m;
    mu[g] = m;
    rstd[g] = rsqrtf(var + 1e-5f);
}

// ---------------- LN + transpose NCHW -> NHWC (bf16 out)
__global__ __launch_bounds__(256)
void ln_transpose(const u16* __restrict__ x, const int* __restrict__ flag,
                  const float* __restrict__ mu, const float* __restrict__ rstd,
                  const u16* __restrict__ lnw, const u16* __restrict__ lnb,
                  u16* __restrict__ xt) {
    int isf32 = *flag;
    __shared__ u16 T[64][72];                     // [n_local][c_local], padded
    int b = blockIdx.x >> 8;
    int n0 = (blockIdx.x & 255) * 64;
    int c0 = blockIdx.y * 64;
    int t = threadIdx.x;
#pragma unroll
    for (int l = 0; l < 2; ++l) {
        int idx = t + l * 256;
        int cl = idx >> 3, nch = (idx & 7) * 8;
        float vals[8];
        load8(x, ((size_t)(b * DIM + c0 + cl)) * NPIX + n0 + nch, isf32, vals);
        float w = bf2f(lnw[c0 + cl]), bb = bf2f(lnb[c0 + cl]);
#pragma unroll
        for (int j = 0; j < 8; ++j) {
            int g = b * NPIX + n0 + nch + j;
            float v = (vals[j] - mu[g]) * rstd[g] * w + bb;
            T[nch + j][cl] = f2bf(v);
        }
    }
    __syncthreads();
#pragma unroll
    for (int l = 0; l < 2; ++l) {
        int idx = t + l * 256;
        int nl = idx >> 3, cch = (idx & 7) * 8;
        uint4 d = *(const uint4*)&T[nl][cch];
        *(uint4*)(xt + (size_t)(b * NPIX + n0 + nl) * DIM + c0 + cch) = d;
    }
}

// ---------------- GEMM: C[M][ldc] = A[M][256] @ Bw[Nout][256]^T + bias (+addt)
template <int HAS_ADD>
__global__ __launch_bounds__(256)
void gemm_bf16(const u16* __restrict__ A, const u16* __restrict__ Bw,
               const u16* __restrict__ bias, const u16* __restrict__ addt,
               u16* __restrict__ C, int ldc) {
    __shared__ u16 As[128][40];
    __shared__ u16 Bs[128][40];
    const int m0 = blockIdx.x * 128;
    const int n0 = blockIdx.y * 128;
    const int t = threadIdx.x;
    const int lane = t & 63;
    const int wid = t >> 6;
    const int wm = (wid >> 1) * 64;
    const int wn = (wid & 1) * 64;
    const int frow = lane & 15;
    const int koff = (lane >> 4) * 8;
    floatx4 acc[4][4] = {};
    for (int k0 = 0; k0 < 256; k0 += 32) {
#pragma unroll
        for (int l = 0; l < 2; ++l) {
            int idx = t + l * 256;
            int r = idx >> 2, ch = (idx & 3) * 8;
            *(uint4*)&As[r][ch] = *(const uint4*)(A + (size_t)(m0 + r) * 256 + k0 + ch);
            *(uint4*)&Bs[r][ch] = *(const uint4*)(Bw + (size_t)(n0 + r) * 256 + k0 + ch);
        }
        __syncthreads();
        short8 af[4], bfr[4];
#pragma unroll
        for (int i = 0; i < 4; ++i) {
            af[i] = *(const short8*)&As[wm + i * 16 + frow][koff];
            bfr[i] = *(const short8*)&Bs[wn + i * 16 + frow][koff];
        }
#pragma unroll
        for (int i = 0; i < 4; ++i)
#pragma unroll
            for (int j = 0; j < 4; ++j)
                acc[i][j] = __builtin_amdgcn_mfma_f32_16x16x32_bf16(af[i], bfr[j], acc[i][j], 0, 0, 0);
        __syncthreads();
    }
    const int col = lane & 15;
    const int r0 = (lane >> 4) * 4;
#pragma unroll
    for (int j = 0; j < 4; ++j) {
        int o = n0 + wn + j * 16 + col;
        float bv = bf2f(bias[o]);
#pragma unroll
        for (int i = 0; i < 4; ++i) {
#pragma unroll
            for (int r = 0; r < 4; ++r) {
                int m = m0 + wm + i * 16 + r0 + r;
                size_t off = (size_t)m * ldc + o;
                float v = acc[i][j][r] + bv;
                if (HAS_ADD) v += bf2f(addt[off]);
                C[off] = f2bf(v);
            }
        }
    }
}

// ---------------- depthwise 3x3 SAME, NHWC, optional bias / gelu
__global__ __launch_bounds__(256)
void dwconv3_nhwc(const u16* __restrict__ in, int in_stride, int in_off,
                  const u16* __restrict__ w9, const u16* __restrict__ bias,
                  u16* __restrict__ out, int out_stride, int out_off,
                  int C, int do_gelu) {
    extern __shared__ float wsm[];                 // [9][C]
    int t = threadIdx.x;
    for (int i = t; i < C * 9; i += 256) {
        int c = i / 9, tap = i % 9;
        wsm[tap * C + c] = bf2f(w9[i]);
    }
    __syncthreads();
    const int tpp = C >> 3;                        // threads per pixel
    const int ppb = 256 / tpp;
    int pix = blockIdx.x * ppb + t / tpp;
    int c8 = (t % tpp) * 8;
    int b = pix >> 14, n = pix & (NPIX - 1);
    int y = n >> 7, x = n & 127;
    float acc[8] = {0, 0, 0, 0, 0, 0, 0, 0};
    const u16* base = in + (size_t)(b * NPIX) * in_stride + in_off + c8;
#pragma unroll
    for (int dy = -1; dy <= 1; ++dy) {
        int yy = y + dy;
        if ((unsigned)yy >= 128u) continue;
#pragma unroll
        for (int dx = -1; dx <= 1; ++dx) {
            int xx = x + dx;
            if ((unsigned)xx >= 128u) continue;
            uint4 d = *(const uint4*)(base + (size_t)(yy * 128 + xx) * in_stride);
            u16 v[8]; *(uint4*)v = d;
            int tap = (dy + 1) * 3 + (dx + 1);
            const float4* wp = (const float4*)&wsm[tap * C + c8];
            float4 w0 = wp[0], w1 = wp[1];
            acc[0] += bf2f(v[0]) * w0.x; acc[1] += bf2f(v[1]) * w0.y;
            acc[2] += bf2f(v[2]) * w0.z; acc[3] += bf2f(v[3]) * w0.w;
            acc[4] += bf2f(v[4]) * w1.x; acc[5] += bf2f(v[5]) * w1.y;
            acc[6] += bf2f(v[6]) * w1.z; acc[7] += bf2f(v[7]) * w1.w;
        }
    }
    u16 o[8];
#pragma unroll
    for (int j = 0; j < 8; ++j) {
        float r = acc[j];
        if (bias) r += bf2f(bias[c8 + j]);
        if (do_gelu) r = gelu_tanh(r);
        o[j] = f2bf(r);
    }
    *(uint4*)(out + (size_t)pix * out_stride + out_off + c8) = *(uint4*)o;
}

__global__ __launch_bounds__(256)
void finalize_scales(const float* __restrict__ qss, const float* __restrict__ kss,
                     float* __restrict__ qsc, float* __restrict__ ksc) {
    int i = blockIdx.x * 256 + threadIdx.x;        // 2048
    qsc[i] = 1.f / fmaxf(sqrtf(qss[i]), 1e-12f);
    ksc[i] = 1.f / fmaxf(sqrtf(kss[i]), 1e-12f);
}

// ---------------- Gram: partial[blk][h,i,j] = sum_{n in chunk} q[n][h*32+i] * k[n][h*32+j]
// Fused: also accumulates per-channel sum-of-squares of q and k (replaces colsumsq).
// Sync-free, LDS-free: q loads coalesced (lane t = channel t); k loads are
// half-wave-identical uint4 broadcasts merged by the coalescer. Each block writes a
// private 8192-float partial (no atomic storm); softmax32 reduces the 128 partials.
__global__ __launch_bounds__(256)
void gram_kernel(const u16* __restrict__ qT, const u16* __restrict__ kvT,
                 float* __restrict__ Gpart, float* __restrict__ qss,
                 float* __restrict__ kss) {
    int blk = blockIdx.x;                          // 8 b * 128 chunks
    int b = blk >> 7, chunk = blk & 127;
    int t = threadIdx.x;                           // channel; h = t>>5, i = t&31
    int hbase = t & 0xE0;                          // h*32
    int row0 = b * NPIX + chunk * 128;
    const u16* qp = qT + (size_t)row0 * 256 + t;
    const u16* kp = kvT + (size_t)row0 * 512;      // k at column offset 0
    float acc[32];
#pragma unroll
    for (int j = 0; j < 32; ++j) acc[j] = 0.f;
    float qs2 = 0.f, ks2 = 0.f;
#pragma unroll 2
    for (int r = 0; r < 128; ++r) {
        float qv = bf2f(qp[(size_t)r * 256]);
        const u16* krow = kp + (size_t)r * 512;
        float kt = bf2f(krow[t]);
        qs2 += qv * qv;
        ks2 += kt * kt;
        uint4 k0 = *(const uint4*)(krow + hbase);
        uint4 k1 = *(const uint4*)(krow + hbase + 8);
        uint4 k2 = *(const uint4*)(krow + hbase + 16);
        uint4 k3 = *(const uint4*)(krow + hbase + 24);
        u16 kv16[32];
        *(uint4*)(kv16 + 0)  = k0;
        *(uint4*)(kv16 + 8)  = k1;
        *(uint4*)(kv16 + 16) = k2;
        *(uint4*)(kv16 + 24) = k3;
#pragma unroll
        for (int j = 0; j < 32; ++j) acc[j] += qv * bf2f(kv16[j]);
    }
    float* gp = Gpart + (size_t)blk * 8192 + t * 32;
#pragma unroll
    for (int j = 0; j < 32; j += 4)
        *(float4*)(gp + j) = make_float4(acc[j], acc[j + 1], acc[j + 2], acc[j + 3]);
    atomicAdd(&qss[b * 256 + t], qs2);
    atomicAdd(&kss[b * 256 + t], ks2);
}

// ---------------- reduce 128 gram partials, apply scales + temperature, softmax over j
__global__ __launch_bounds__(1024)
void softmax32(const float* __restrict__ Gpart, const float* __restrict__ qsc,
               const float* __restrict__ ksc, const u16* __restrict__ temp,
               float* __restrict__ attn) {
    int bh = blockIdx.x;
    int b = bh >> 3, h = bh & 7;
    int t = threadIdx.x;
    int i = t >> 5, j = t & 31;
    const float* gp = Gpart + (size_t)b * 128 * 8192 + (size_t)((h * 32 + i) * 32 + j);
    float s0 = 0.f, s1 = 0.f, s2 = 0.f, s3 = 0.f;
    for (int p = 0; p < 128; p += 4) {
        s0 += gp[(size_t)p * 8192];
        s1 += gp[(size_t)(p + 1) * 8192];
        s2 += gp[(size_t)(p + 2) * 8192];
        s3 += gp[(size_t)(p + 3) * 8192];
    }
    float qs = qsc[b * 256 + h * 32 + i];
    float ks = ksc[b * 256 + h * 32 + j];
    float tm = bf2f(temp[h]);
    float v = ((s0 + s1) + (s2 + s3)) * qs * ks * tm;
    float m = v;
    for (int s = 16; s; s >>= 1) m = fmaxf(m, __shfl_xor(m, s, 32));
    float e = __expf(v - m);
    float sum = e;
    for (int s = 16; s; s >>= 1) sum += __shfl_xor(sum, s, 32);
    attn[((size_t)(b * 8 + h) * 32 + i) * 32 + j] = e / sum;
}

// ---------------- out[n][c] = sum_j attn[h,i,j] * v[n][h*32+j]  (channels-last out)
__global__ __launch_bounds__(256)
void attnv_kernel(const float* __restrict__ attn, const u16* __restrict__ kvT,
                  u16* __restrict__ outT) {
    __shared__ float at[8][32][33];
    __shared__ u16 vs[8][256];
    int b = blockIdx.x >> 7, chunk = blockIdx.x & 127;
    int t = threadIdx.x;
    for (int idx = t; idx < 8192; idx += 256) {
        int hh = idx >> 10, rem = idx & 1023;
        at[hh][rem >> 5][rem & 31] = attn[(size_t)b * 8192 + idx];
    }
    int h = t >> 5, i = t & 31;
    int row0 = b * NPIX + chunk * 128;
    int rr = t >> 5, cc = (t & 31) * 8;
    for (int r8 = 0; r8 < 128; r8 += 8) {
        __syncthreads();
        *(uint4*)&vs[rr][cc] = *(const uint4*)(kvT + (size_t)(row0 + r8 + rr) * 512 + 256 + cc);
        __syncthreads();
#pragma unroll
        for (int r = 0; r < 8; ++r) {
            float a = 0.f;
#pragma unroll
            for (int j = 0; j < 32; j += 4) {
                uint2 vd = *(const uint2*)&vs[r][h * 32 + j];
                u16 v4[4]; *(uint2*)v4 = vd;
                a += at[h][i][j]     * bf2f(v4[0]);
                a += at[h][i][j + 1] * bf2f(v4[1]);
                a += at[h][i][j + 2] * bf2f(v4[2]);
                a += at[h][i][j + 3] * bf2f(v4[3]);
            }
            outT[(size_t)(row0 + r8 + r) * 256 + t] = f2bf(a);
        }
    }
}

// ---------------- transpose NHWC Fp back to NCHW, add hx, write out (flag-aware format)
__global__ __launch_bounds__(256)
void final_out(const u16* __restrict__ Fp, const u16* __restrict__ hx,
               const int* __restrict__ flag, u16* __restrict__ out) {
    int isf32 = *flag;
    __shared__ u16 T[64][72];
    int b = blockIdx.x >> 8;
    int n0 = (blockIdx.x & 255) * 64;
    int c0 = blockIdx.y * 64;
    int t = threadIdx.x;
#pragma unroll
    for (int l = 0; l < 2; ++l) {
        int idx = t + l * 256;
        int nl = idx >> 3, cch = (idx & 7) * 8;
        *(uint4*)&T[nl][cch] = *(const uint4*)(Fp + (size_t)(b * NPIX + n0 + nl) * 256 + c0 + cch);
    }
    __syncthreads();
#pragma unroll
    for (int l = 0; l < 2; ++l) {
        int idx = t + l * 256;
        int cl = idx >> 3, nch = (idx & 7) * 8;
        size_t g = (size_t)(b * DIM + c0 + cl) * NPIX + n0 + nch;
        float hv[8];
        load8(hx, g, isf32, hv);
        float r[8];
#pragma unroll
        for (int j = 0; j < 8; ++j) r[j] = bf2f(T[nch + j][cl]) + hv[j];
        if (isf32) {
            float* o = (float*)out + g;
            *(float4*)o       = make_float4(r[0], r[1], r[2], r[3]);
            *(float4*)(o + 4) = make_float4(r[4], r[5], r[6], r[7]);
        } else {
            u16 ov[8];
#pragma unroll
            for (int j = 0; j < 8; ++j) ov[j] = f2bf(r[j]);
            *(uint4*)(out + g) = *(uint4*)ov;
        }
    }
}

__global__ void ws_marker(u16* out) {
    if (threadIdx.x < 64) ((uint32_t*)out)[threadIdx.x] = 0x46402400u;  // 12345.0f pattern
}

extern "C" void kernel_launch(void* const* d_in, const int* in_sizes, int n_in,
                              void* d_out, int out_size, void* d_ws, size_t ws_size,
                              hipStream_t stream) {
    const u16* x    = (const u16*)d_in[0];
    const u16* hx   = (const u16*)d_in[1];
    u16* outp = (u16*)d_out;

    char* ws = (char*)d_ws;
    float* F = (float*)ws;
    float* mu_x   = F;
    float* rstd_x = F + 131072;
    float* mu_h   = F + 262144;
    float* rstd_h = F + 393216;
    float* qss    = F + 524288;
    float* kss    = F + 526336;
    float* qsc    = F + 528384;
    float* ksc    = F + 530432;
    float* attn   = F + 598016;
    int*   dflag  = (int*)(F + 663552);
    u16*   W      = (u16*)(ws + 2752512);          // canonical bf16 params
    u16* R1 = (u16*)(ws + (((size_t)4)   << 20));   // 64 MiB
    u16* R2 = (u16*)(ws + (((size_t)68)  << 20));   // 64 MiB
    u16* R3 = (u16*)(ws + (((size_t)132) << 20));   // 128 MiB
    u16* R4 = (u16*)(ws + (((size_t)260) << 20));   // 128 MiB
    float* Gpart = (float*)R2;   // 32 MiB of gram partials; R2 is dead at gram time
                                 // (q-gemm output already consumed by dwconv) and is
                                 // rewritten only later by attnv (stream-ordered safe)

    size_t need = ((size_t)388) << 20;
    if (ws_size < need) {
        ws_marker<<<1, 64, 0, stream>>>(outp);
        return;
    }

    // canonical param element offsets in W
    const int O_QW = 0, O_KVW = 65536, O_AOW = 196608, O_QB = 262144, O_KVB = 262400,
              O_AOB = 262912, O_LN1W = 263168, O_LN1B = 263424, O_LN2W = 263680,
              O_LN2B = 263936, O_QDWW = 264192, O_QDWB = 266496, O_KVDWW = 266752,
              O_KVDWB = 271360, O_PE1 = 271872, O_PE2 = 274176, O_TEMP = 276480;

    WArgs wa;
    const int srcidx[17] = {6, 10, 14, 7, 11, 15, 2, 3, 4, 5, 8, 9, 12, 13, 16, 17, 18};
    const int offs[17]   = {O_QW, O_KVW, O_AOW, O_QB, O_KVB, O_AOB, O_LN1W, O_LN1B,
                            O_LN2W, O_LN2B, O_QDWW, O_QDWB, O_KVDWW, O_KVDWB,
                            O_PE1, O_PE2, O_TEMP};
    const int ns[17]     = {65536, 131072, 65536, 256, 512, 256, 256, 256, 256, 256,
                            2304, 256, 4608, 512, 2304, 2304, 8};
    for (int i = 0; i < 17; ++i) { wa.src[i] = d_in[srcidx[i]]; wa.off[i] = offs[i]; wa.n[i] = ns[i]; }

    detect_dtype<<<1, 256, 0, stream>>>(x, dflag);
    convert_params<<<dim3(16, 17), 256, 0, stream>>>(wa, dflag, W);

    // zero sumsq accumulators (qss/kss/qsc/ksc region)
    hipMemsetAsync(ws + (size_t)524288 * 4, 0, (size_t)(532480 - 524288) * 4, stream);

    ln_stats<<<512, 256, 0, stream>>>(x, dflag, mu_x, rstd_x);
    ln_stats<<<512, 256, 0, stream>>>(hx, dflag, mu_h, rstd_h);

    ln_transpose<<<dim3(2048, 4), 256, 0, stream>>>(x, dflag, mu_x, rstd_x, W + O_LN1W, W + O_LN1B, R1);
    gemm_bf16<0><<<dim3(1024, 2), 256, 0, stream>>>(R1, W + O_QW, W + O_QB, nullptr, R2, 256);

    ln_transpose<<<dim3(2048, 4), 256, 0, stream>>>(hx, dflag, mu_h, rstd_h, W + O_LN2W, W + O_LN2B, R1);
    gemm_bf16<0><<<dim3(1024, 4), 256, 0, stream>>>(R1, W + O_KVW, W + O_KVB, nullptr, R3, 512);

    dwconv3_nhwc<<<16384, 256, 9 * 256 * 4, stream>>>(R2, 256, 0, W + O_QDWW, W + O_QDWB, R1, 256, 0, 256, 0);
    dwconv3_nhwc<<<32768, 256, 9 * 512 * 4, stream>>>(R3, 512, 0, W + O_KVDWW, W + O_KVDWB, R4, 512, 0, 512, 0);

    // fused gram + colsumsq: 1024 sync-free blocks, per-block partial G
    gram_kernel<<<1024, 256, 0, stream>>>(R1, R4, Gpart, qss, kss);
    finalize_scales<<<8, 256, 0, stream>>>(qss, kss, qsc, ksc);
    softmax32<<<64, 1024, 0, stream>>>(Gpart, qsc, ksc, W + O_TEMP, attn);
    attnv_kernel<<<1024, 256, 0, stream>>>(attn, R4, R2);

    dwconv3_nhwc<<<16384, 256, 9 * 256 * 4, stream>>>(R4, 512, 256, W + O_PE1, nullptr, R3, 256, 0, 256, 1);
    dwconv3_nhwc<<<16384, 256, 9 * 256 * 4, stream>>>(R3, 256, 0, W + O_PE2, nullptr, R1, 256, 0, 256, 0);

    gemm_bf16<1><<<dim3(1024, 2), 256, 0, stream>>>(R2, W + O_AOW, W + O_AOB, R1, R3, 256);
    final_out<<<dim3(2048, 4), 256, 0, stream>>>(R3, hx, dflag, outp);
}

// Round 2
// 1314.003 us; speedup vs baseline: 1.2100x; 1.0558x over previous
//
#include <hip/hip_runtime.h>
#include <cstdio>
#include <cstdint>

typedef unsigned short u16;
typedef short short8 __attribute__((ext_vector_type(8)));
typedef float floatx4 __attribute__((ext_vector_type(4)));

#define NPIX 16384      // 128*128
#define DIM 256

__device__ inline float bf2f(u16 v) {
    return __uint_as_float(((uint32_t)v) << 16);
}
__device__ inline u16 f2bf(float f) {
    uint32_t u = __float_as_uint(f);
    u += 0x7fffu + ((u >> 16) & 1u);
    return (u16)(u >> 16);
}
// gelu(x) = x * sigmoid(2*0.79788456*(x+0.044715x^3)) — exact rewrite of tanh form
__device__ inline float gelu_fast(float x) {
    float x3 = x * x * x;
    float z2 = 1.5957691216057308f * (x + 0.044715f * x3);   // 2*sqrt(2/pi)*(...)
    return x * __builtin_amdgcn_rcpf(1.f + __expf(-z2));
}
// flag-aware load of 8 consecutive elements from a raw input tensor
__device__ inline void load8(const u16* p, size_t idx, int isf32, float out[8]) {
    if (isf32) {
        const float4* f = (const float4*)((const float*)p + idx);
        float4 a = f[0], b = f[1];
        out[0] = a.x; out[1] = a.y; out[2] = a.z; out[3] = a.w;
        out[4] = b.x; out[5] = b.y; out[6] = b.z; out[7] = b.w;
    } else {
        uint4 d = *(const uint4*)(p + idx);
        u16 v[8]; *(uint4*)v = d;
#pragma unroll
        for (int j = 0; j < 8; ++j) out[j] = bf2f(v[j]);
    }
}

// ---------------- dtype sniffer: low u16 of each word is a plausible bf16 only for bf16 data
__global__ __launch_bounds__(256)
void detect_dtype(const u16* __restrict__ x, int* __restrict__ flag) {
    __shared__ int sh[256];
    int t = threadIdx.x;
    const uint32_t* w = (const uint32_t*)x;
    int cnt = 0;
    for (int i = t; i < 4096; i += 256) {
        int e = (w[i] >> 7) & 0xFF;
        if (e >= 110 && e <= 134) cnt++;
    }
    sh[t] = cnt;
    __syncthreads();
    if (t == 0) {
        int s = 0;
        for (int i = 0; i < 256; ++i) s += sh[i];
        *flag = (s < 2048) ? 1 : 0;    // 1 => inputs are float32
    }
}

// ---------------- convert all parameter tensors to canonical bf16 in ws
struct WArgs {
    const void* src[17];
    int off[17];
    int n[17];
};
__global__ __launch_bounds__(256)
void convert_params(WArgs a, const int* __restrict__ flag, u16* __restrict__ dst) {
    int isf32 = *flag;
    int w = blockIdx.y;
    const void* s = a.src[w];
    u16* d = dst + a.off[w];
    int n = a.n[w];
    for (int i = blockIdx.x * 256 + threadIdx.x; i < n; i += gridDim.x * 256)
        d[i] = isf32 ? f2bf(((const float*)s)[i]) : ((const u16*)s)[i];
}

// ---------------- LN stats: per-pixel mean/rstd over 256 channels (NCHW input)
__global__ __launch_bounds__(256)
void ln_stats(const u16* __restrict__ x, const int* __restrict__ flag,
              float* __restrict__ mu, float* __restrict__ rstd) {
    int isf32 = *flag;
    int g = blockIdx.x * 256 + threadIdx.x;       // pixel id 0..131071
    int b = g >> 14, n = g & (NPIX - 1);
    float s = 0.f, s2 = 0.f;
    if (isf32) {
        const float* p = (const float*)x + (size_t)b * DIM * NPIX + n;
        for (int c = 0; c < DIM; ++c) { float v = p[(size_t)c * NPIX]; s += v; s2 += v * v; }
    } else {
        const u16* p = x + (size_t)b * DIM * NPIX + n;
        for (int c = 0; c < DIM; ++c) { float v = bf2f(p[(size_t)c * NPIX]); s += v; s2 += v * v; }
    }
    float m = s * (1.f / 256.f);
    float var = s2 * (1.f / 256.f) - m * m;
    mu[g] = m;
    rstd[g] = rsqrtf(var + 1e-5f);
}

// ---------------- LN + transpose NCHW -> NHWC (bf16 out)
__global__ __launch_bounds__(256)
void ln_transpose(const u16* __restrict__ x, const int* __restrict__ flag,
                  const float* __restrict__ mu, const float* __restrict__ rstd,
                  const u16* __restrict__ lnw, const u16* __restrict__ lnb,
                  u16* __restrict__ xt) {
    int isf32 = *flag;
    __shared__ u16 T[64][72];                     // [n_local][c_local], padded
    int b = blockIdx.x >> 8;
    int n0 = (blockIdx.x & 255) * 64;
    int c0 = blockIdx.y * 64;
    int t = threadIdx.x;
#pragma unroll
    for (int l = 0; l < 2; ++l) {
        int idx = t + l * 256;
        int cl = idx >> 3, nch = (idx & 7) * 8;
        float vals[8];
        load8(x, ((size_t)(b * DIM + c0 + cl)) * NPIX + n0 + nch, isf32, vals);
        float w = bf2f(lnw[c0 + cl]), bb = bf2f(lnb[c0 + cl]);
#pragma unroll
        for (int j = 0; j < 8; ++j) {
            int g = b * NPIX + n0 + nch + j;
            float v = (vals[j] - mu[g]) * rstd[g] * w + bb;
            T[nch + j][cl] = f2bf(v);
        }
    }
    __syncthreads();
#pragma unroll
    for (int l = 0; l < 2; ++l) {
        int idx = t + l * 256;
        int nl = idx >> 3, cch = (idx & 7) * 8;
        uint4 d = *(const uint4*)&T[nl][cch];
        *(uint4*)(xt + (size_t)(b * NPIX + n0 + nl) * DIM + c0 + cch) = d;
    }
}

// ---------------- GEMM: C[M][ldc] = A[M][256] @ Bw[Nout][256]^T + bias (+addt)
template <int HAS_ADD>
__global__ __launch_bounds__(256)
void gemm_bf16(const u16* __restrict__ A, const u16* __restrict__ Bw,
               const u16* __restrict__ bias, const u16* __restrict__ addt,
               u16* __restrict__ C, int ldc) {
    __shared__ u16 As[128][40];
    __shared__ u16 Bs[128][40];
    const int m0 = blockIdx.x * 128;
    const int n0 = blockIdx.y * 128;
    const int t = threadIdx.x;
    const int lane = t & 63;
    const int wid = t >> 6;
    const int wm = (wid >> 1) * 64;
    const int wn = (wid & 1) * 64;
    const int frow = lane & 15;
    const int koff = (lane >> 4) * 8;
    floatx4 acc[4][4] = {};
    for (int k0 = 0; k0 < 256; k0 += 32) {
#pragma unroll
        for (int l = 0; l < 2; ++l) {
            int idx = t + l * 256;
            int r = idx >> 2, ch = (idx & 3) * 8;
            *(uint4*)&As[r][ch] = *(const uint4*)(A + (size_t)(m0 + r) * 256 + k0 + ch);
            *(uint4*)&Bs[r][ch] = *(const uint4*)(Bw + (size_t)(n0 + r) * 256 + k0 + ch);
        }
        __syncthreads();
        short8 af[4], bfr[4];
#pragma unroll
        for (int i = 0; i < 4; ++i) {
            af[i] = *(const short8*)&As[wm + i * 16 + frow][koff];
            bfr[i] = *(const short8*)&Bs[wn + i * 16 + frow][koff];
        }
#pragma unroll
        for (int i = 0; i < 4; ++i)
#pragma unroll
            for (int j = 0; j < 4; ++j)
                acc[i][j] = __builtin_amdgcn_mfma_f32_16x16x32_bf16(af[i], bfr[j], acc[i][j], 0, 0, 0);
        __syncthreads();
    }
    const int col = lane & 15;
    const int r0 = (lane >> 4) * 4;
#pragma unroll
    for (int j = 0; j < 4; ++j) {
        int o = n0 + wn + j * 16 + col;
        float bv = bf2f(bias[o]);
#pragma unroll
        for (int i = 0; i < 4; ++i) {
#pragma unroll
            for (int r = 0; r < 4; ++r) {
                int m = m0 + wm + i * 16 + r0 + r;
                size_t off = (size_t)m * ldc + o;
                float v = acc[i][j][r] + bv;
                if (HAS_ADD) v += bf2f(addt[off]);
                C[off] = f2bf(v);
            }
        }
    }
}

// ---------------- depthwise 3x3 SAME, NHWC, register weights, 4 x-pixels/thread
// Each thread: 8 channels x 4 consecutive x. Weights (72 floats) live in VGPRs;
// no LDS, no syncthreads. All tap/pixel indexing is compile-time (C is template).
template <int C, int HAS_BIAS, int DO_GELU>
__global__ __launch_bounds__(256)
void dwconv3_reg(const u16* __restrict__ in, int in_stride, int in_off,
                 const u16* __restrict__ w9, const u16* __restrict__ bias,
                 u16* __restrict__ out, int out_stride, int out_off) {
    constexpr int TPP = C / 8;              // threads per 4-pixel group
    constexpr int GRP = 256 / TPP;          // groups per block
    constexpr int XSEG = 128 / (GRP * 4);   // blocks per row
    int t = threadIdx.x;
    int cl = t & (TPP - 1);
    int g = t / TPP;
    int c8 = cl * 8;
    int blk = blockIdx.x;
    int xs = blk & (XSEG - 1);
    int tmp = blk / XSEG;
    int y = tmp & 127;
    int b = tmp >> 7;
    int x0 = xs * (GRP * 4) + g * 4;

    // per-thread weights: 72 contiguous u16 at w9 + c8*9 (16B-aligned)
    u16 wl[72];
#pragma unroll
    for (int i = 0; i < 9; ++i)
        *((uint4*)wl + i) = *((const uint4*)(w9 + c8 * 9) + i);
    float wgt[9][8];
#pragma unroll
    for (int tap = 0; tap < 9; ++tap)
#pragma unroll
        for (int j = 0; j < 8; ++j)
            wgt[tap][j] = bf2f(wl[j * 9 + tap]);

    float acc[4][8] = {};
#pragma unroll
    for (int dy = -1; dy <= 1; ++dy) {
        int yy = y + dy;
        if ((unsigned)yy >= 128u) continue;            // block-uniform branch
        const u16* rp = in + (size_t)(b * NPIX + yy * 128) * in_stride + in_off + c8;
#pragma unroll
        for (int ci = 0; ci < 6; ++ci) {
            int cc = x0 - 1 + ci;
            if ((unsigned)cc >= 128u) continue;        // edge threads only
            uint4 d = *(const uint4*)(rp + (size_t)cc * in_stride);
            u16 v[8]; *(uint4*)v = d;
            float fv[8];
#pragma unroll
            for (int j = 0; j < 8; ++j) fv[j] = bf2f(v[j]);
#pragma unroll
            for (int dx = -1; dx <= 1; ++dx) {
                int p = ci - 1 - dx;                   // compile-time
                if (p < 0 || p > 3) continue;
                int tap = (dy + 1) * 3 + (dx + 1);
#pragma unroll
                for (int j = 0; j < 8; ++j) acc[p][j] += fv[j] * wgt[tap][j];
            }
        }
    }

    float bi[8];
    if (HAS_BIAS) {
        uint4 bd = *(const uint4*)(bias + c8);
        u16 bv[8]; *(uint4*)bv = bd;
#pragma unroll
        for (int j = 0; j < 8; ++j) bi[j] = bf2f(bv[j]);
    }
    u16* op = out + (size_t)(b * NPIX + y * 128 + x0) * out_stride + out_off + c8;
#pragma unroll
    for (int p = 0; p < 4; ++p) {
        u16 o[8];
#pragma unroll
        for (int j = 0; j < 8; ++j) {
            float r = acc[p][j];
            if (HAS_BIAS) r += bi[j];
            if (DO_GELU) r = gelu_fast(r);
            o[j] = f2bf(r);
        }
        *(uint4*)(op + (size_t)p * out_stride) = *(uint4*)o;
    }
}

__global__ __launch_bounds__(256)
void finalize_scales(const float* __restrict__ qss, const float* __restrict__ kss,
                     float* __restrict__ qsc, float* __restrict__ ksc) {
    int i = blockIdx.x * 256 + threadIdx.x;        // 2048
    qsc[i] = 1.f / fmaxf(sqrtf(qss[i]), 1e-12f);
    ksc[i] = 1.f / fmaxf(sqrtf(kss[i]), 1e-12f);
}

// ---------------- Gram: partial[blk][h,i,j] = sum_{n in chunk} q[n][h*32+i] * k[n][h*32+j]
// Fused: also accumulates per-channel sum-of-squares of q and k (replaces colsumsq).
__global__ __launch_bounds__(256)
void gram_kernel(const u16* __restrict__ qT, const u16* __restrict__ kvT,
                 float* __restrict__ Gpart, float* __restrict__ qss,
                 float* __restrict__ kss) {
    int blk = blockIdx.x;                          // 8 b * 128 chunks
    int b = blk >> 7, chunk = blk & 127;
    int t = threadIdx.x;                           // channel; h = t>>5, i = t&31
    int hbase = t & 0xE0;                          // h*32
    int row0 = b * NPIX + chunk * 128;
    const u16* qp = qT + (size_t)row0 * 256 + t;
    const u16* kp = kvT + (size_t)row0 * 512;      // k at column offset 0
    float acc[32];
#pragma unroll
    for (int j = 0; j < 32; ++j) acc[j] = 0.f;
    float qs2 = 0.f, ks2 = 0.f;
#pragma unroll 2
    for (int r = 0; r < 128; ++r) {
        float qv = bf2f(qp[(size_t)r * 256]);
        const u16* krow = kp + (size_t)r * 512;
        float kt = bf2f(krow[t]);
        qs2 += qv * qv;
        ks2 += kt * kt;
        uint4 k0 = *(const uint4*)(krow + hbase);
        uint4 k1 = *(const uint4*)(krow + hbase + 8);
        uint4 k2 = *(const uint4*)(krow + hbase + 16);
        uint4 k3 = *(const uint4*)(krow + hbase + 24);
        u16 kv16[32];
        *(uint4*)(kv16 + 0)  = k0;
        *(uint4*)(kv16 + 8)  = k1;
        *(uint4*)(kv16 + 16) = k2;
        *(uint4*)(kv16 + 24) = k3;
#pragma unroll
        for (int j = 0; j < 32; ++j) acc[j] += qv * bf2f(kv16[j]);
    }
    float* gp = Gpart + (size_t)blk * 8192 + t * 32;
#pragma unroll
    for (int j = 0; j < 32; j += 4)
        *(float4*)(gp + j) = make_float4(acc[j], acc[j + 1], acc[j + 2], acc[j + 3]);
    atomicAdd(&qss[b * 256 + t], qs2);
    atomicAdd(&kss[b * 256 + t], ks2);
}

// ---------------- reduce 128 gram partials, apply scales + temperature, softmax over j
__global__ __launch_bounds__(1024)
void softmax32(const float* __restrict__ Gpart, const float* __restrict__ qsc,
               const float* __restrict__ ksc, const u16* __restrict__ temp,
               float* __restrict__ attn) {
    int bh = blockIdx.x;
    int b = bh >> 3, h = bh & 7;
    int t = threadIdx.x;
    int i = t >> 5, j = t & 31;
    const float* gp = Gpart + (size_t)b * 128 * 8192 + (size_t)((h * 32 + i) * 32 + j);
    float s0 = 0.f, s1 = 0.f, s2 = 0.f, s3 = 0.f;
    for (int p = 0; p < 128; p += 4) {
        s0 += gp[(size_t)p * 8192];
        s1 += gp[(size_t)(p + 1) * 8192];
        s2 += gp[(size_t)(p + 2) * 8192];
        s3 += gp[(size_t)(p + 3) * 8192];
    }
    float qs = qsc[b * 256 + h * 32 + i];
    float ks = ksc[b * 256 + h * 32 + j];
    float tm = bf2f(temp[h]);
    float v = ((s0 + s1) + (s2 + s3)) * qs * ks * tm;
    float m = v;
    for (int s = 16; s; s >>= 1) m = fmaxf(m, __shfl_xor(m, s, 32));
    float e = __expf(v - m);
    float sum = e;
    for (int s = 16; s; s >>= 1) sum += __shfl_xor(sum, s, 32);
    attn[((size_t)(b * 8 + h) * 32 + i) * 32 + j] = e / sum;
}

// ---------------- out[n][c] = sum_j attn[h,i,j] * v[n][h*32+j]  (channels-last out)
__global__ __launch_bounds__(256)
void attnv_kernel(const float* __restrict__ attn, const u16* __restrict__ kvT,
                  u16* __restrict__ outT) {
    __shared__ float at[8][32][33];
    __shared__ u16 vs[8][256];
    int b = blockIdx.x >> 7, chunk = blockIdx.x & 127;
    int t = threadIdx.x;
    for (int idx = t; idx < 8192; idx += 256) {
        int hh = idx >> 10, rem = idx & 1023;
        at[hh][rem >> 5][rem & 31] = attn[(size_t)b * 8192 + idx];
    }
    int h = t >> 5, i = t & 31;
    int row0 = b * NPIX + chunk * 128;
    int rr = t >> 5, cc = (t & 31) * 8;
    for (int r8 = 0; r8 < 128; r8 += 8) {
        __syncthreads();
        *(uint4*)&vs[rr][cc] = *(const uint4*)(kvT + (size_t)(row0 + r8 + rr) * 512 + 256 + cc);
        __syncthreads();
#pragma unroll
        for (int r = 0; r < 8; ++r) {
            float a = 0.f;
#pragma unroll
            for (int j = 0; j < 32; j += 4) {
                uint2 vd = *(const uint2*)&vs[r][h * 32 + j];
                u16 v4[4]; *(uint2*)v4 = vd;
                a += at[h][i][j]     * bf2f(v4[0]);
                a += at[h][i][j + 1] * bf2f(v4[1]);
                a += at[h][i][j + 2] * bf2f(v4[2]);
                a += at[h][i][j + 3] * bf2f(v4[3]);
            }
            outT[(size_t)(row0 + r8 + r) * 256 + t] = f2bf(a);
        }
    }
}

// ---------------- transpose NHWC Fp back to NCHW, add hx, write out (flag-aware format)
__global__ __launch_bounds__(256)
void final_out(const u16* __restrict__ Fp, const u16* __restrict__ hx,
               const int* __restrict__ flag, u16* __restrict__ out) {
    int isf32 = *flag;
    __shared__ u16 T[64][72];
    int b = blockIdx.x >> 8;
    int n0 = (blockIdx.x & 255) * 64;
    int c0 = blockIdx.y * 64;
    int t = threadIdx.x;
#pragma unroll
    for (int l = 0; l < 2; ++l) {
        int idx = t + l * 256;
        int nl = idx >> 3, cch = (idx & 7) * 8;
        *(uint4*)&T[nl][cch] = *(const uint4*)(Fp + (size_t)(b * NPIX + n0 + nl) * 256 + c0 + cch);
    }
    __syncthreads();
#pragma unroll
    for (int l = 0; l < 2; ++l) {
        int idx = t + l * 256;
        int cl = idx >> 3, nch = (idx & 7) * 8;
        size_t g = (size_t)(b * DIM + c0 + cl) * NPIX + n0 + nch;
        float hv[8];
        load8(hx, g, isf32, hv);
        float r[8];
#pragma unroll
        for (int j = 0; j < 8; ++j) r[j] = bf2f(T[nch + j][cl]) + hv[j];
        if (isf32) {
            float* o = (float*)out + g;
            *(float4*)o       = make_float4(r[0], r[1], r[2], r[3]);
            *(float4*)(o + 4) = make_float4(r[4], r[5], r[6], r[7]);
        } else {
            u16 ov[8];
#pragma unroll
            for (int j = 0; j < 8; ++j) ov[j] = f2bf(r[j]);
            *(uint4*)(out + g) = *(uint4*)ov;
        }
    }
}

__global__ void ws_marker(u16* out) {
    if (threadIdx.x < 64) ((uint32_t*)out)[threadIdx.x] = 0x46402400u;  // 12345.0f pattern
}

extern "C" void kernel_launch(void* const* d_in, const int* in_sizes, int n_in,
                              void* d_out, int out_size, void* d_ws, size_t ws_size,
                              hipStream_t stream) {
    const u16* x    = (const u16*)d_in[0];
    const u16* hx   = (const u16*)d_in[1];
    u16* outp = (u16*)d_out;

    char* ws = (char*)d_ws;
    float* F = (float*)ws;
    float* mu_x   = F;
    float* rstd_x = F + 131072;
    float* mu_h   = F + 262144;
    float* rstd_h = F + 393216;
    float* qss    = F + 524288;
    float* kss    = F + 526336;
    float* qsc    = F + 528384;
    float* ksc    = F + 530432;
    float* attn   = F + 598016;
    int*   dflag  = (int*)(F + 663552);
    u16*   W      = (u16*)(ws + 2752512);          // canonical bf16 params
    u16* R1 = (u16*)(ws + (((size_t)4)   << 20));   // 64 MiB
    u16* R2 = (u16*)(ws + (((size_t)68)  << 20));   // 64 MiB
    u16* R3 = (u16*)(ws + (((size_t)132) << 20));   // 128 MiB
    u16* R4 = (u16*)(ws + (((size_t)260) << 20));   // 128 MiB
    float* Gpart = (float*)R2;   // 32 MiB of gram partials; R2 is dead at gram time

    size_t need = ((size_t)388) << 20;
    if (ws_size < need) {
        ws_marker<<<1, 64, 0, stream>>>(outp);
        return;
    }

    // canonical param element offsets in W
    const int O_QW = 0, O_KVW = 65536, O_AOW = 196608, O_QB = 262144, O_KVB = 262400,
              O_AOB = 262912, O_LN1W = 263168, O_LN1B = 263424, O_LN2W = 263680,
              O_LN2B = 263936, O_QDWW = 264192, O_QDWB = 266496, O_KVDWW = 266752,
              O_KVDWB = 271360, O_PE1 = 271872, O_PE2 = 274176, O_TEMP = 276480;

    WArgs wa;
    const int srcidx[17] = {6, 10, 14, 7, 11, 15, 2, 3, 4, 5, 8, 9, 12, 13, 16, 17, 18};
    const int offs[17]   = {O_QW, O_KVW, O_AOW, O_QB, O_KVB, O_AOB, O_LN1W, O_LN1B,
                            O_LN2W, O_LN2B, O_QDWW, O_QDWB, O_KVDWW, O_KVDWB,
                            O_PE1, O_PE2, O_TEMP};
    const int ns[17]     = {65536, 131072, 65536, 256, 512, 256, 256, 256, 256, 256,
                            2304, 256, 4608, 512, 2304, 2304, 8};
    for (int i = 0; i < 17; ++i) { wa.src[i] = d_in[srcidx[i]]; wa.off[i] = offs[i]; wa.n[i] = ns[i]; }

    detect_dtype<<<1, 256, 0, stream>>>(x, dflag);
    convert_params<<<dim3(16, 17), 256, 0, stream>>>(wa, dflag, W);

    // zero sumsq accumulators (qss/kss/qsc/ksc region)
    hipMemsetAsync(ws + (size_t)524288 * 4, 0, (size_t)(532480 - 524288) * 4, stream);

    ln_stats<<<512, 256, 0, stream>>>(x, dflag, mu_x, rstd_x);
    ln_stats<<<512, 256, 0, stream>>>(hx, dflag, mu_h, rstd_h);

    ln_transpose<<<dim3(2048, 4), 256, 0, stream>>>(x, dflag, mu_x, rstd_x, W + O_LN1W, W + O_LN1B, R1);
    gemm_bf16<0><<<dim3(1024, 2), 256, 0, stream>>>(R1, W + O_QW, W + O_QB, nullptr, R2, 256);

    ln_transpose<<<dim3(2048, 4), 256, 0, stream>>>(hx, dflag, mu_h, rstd_h, W + O_LN2W, W + O_LN2B, R1);
    gemm_bf16<0><<<dim3(1024, 4), 256, 0, stream>>>(R1, W + O_KVW, W + O_KVB, nullptr, R3, 512);

    dwconv3_reg<256, 1, 0><<<4096, 256, 0, stream>>>(R2, 256, 0, W + O_QDWW, W + O_QDWB, R1, 256, 0);
    dwconv3_reg<512, 1, 0><<<8192, 256, 0, stream>>>(R3, 512, 0, W + O_KVDWW, W + O_KVDWB, R4, 512, 0);

    // fused gram + colsumsq: 1024 sync-free blocks, per-block partial G
    gram_kernel<<<1024, 256, 0, stream>>>(R1, R4, Gpart, qss, kss);
    finalize_scales<<<8, 256, 0, stream>>>(qss, kss, qsc, ksc);
    softmax32<<<64, 1024, 0, stream>>>(Gpart, qsc, ksc, W + O_TEMP, attn);
    attnv_kernel<<<1024, 256, 0, stream>>>(attn, R4, R2);

    dwconv3_reg<256, 0, 1><<<4096, 256, 0, stream>>>(R4, 512, 256, W + O_PE1, nullptr, R3, 256, 0);
    dwconv3_reg<256, 0, 0><<<4096, 256, 0, stream>>>(R3, 256, 0, W + O_PE2, nullptr, R1, 256, 0);

    gemm_bf16<1><<<dim3(1024, 2), 256, 0, stream>>>(R2, W + O_AOW, W + O_AOB, R1, R3, 256);
    final_out<<<dim3(2048, 4), 256, 0, stream>>>(R3, hx, dflag, outp);
}

// Round 3
// 1256.645 us; speedup vs baseline: 1.2653x; 1.0456x over previous
//
#include <hip/hip_runtime.h>
#include <cstdio>
#include <cstdint>

typedef unsigned short u16;
typedef short short8 __attribute__((ext_vector_type(8)));
typedef float floatx4 __attribute__((ext_vector_type(4)));

#define NPIX 16384      // 128*128
#define DIM 256

__device__ inline float bf2f(u16 v) {
    return __uint_as_float(((uint32_t)v) << 16);
}
__device__ inline u16 f2bf(float f) {
    uint32_t u = __float_as_uint(f);
    u += 0x7fffu + ((u >> 16) & 1u);
    return (u16)(u >> 16);
}
// gelu(x) = x * sigmoid(2*0.79788456*(x+0.044715x^3)) — exact rewrite of tanh form
__device__ inline float gelu_fast(float x) {
    float x3 = x * x * x;
    float z2 = 1.5957691216057308f * (x + 0.044715f * x3);   // 2*sqrt(2/pi)*(...)
    return x * __builtin_amdgcn_rcpf(1.f + __expf(-z2));
}
// flag-aware load of 8 consecutive elements from a raw input tensor
__device__ inline void load8(const u16* p, size_t idx, int isf32, float out[8]) {
    if (isf32) {
        const float4* f = (const float4*)((const float*)p + idx);
        float4 a = f[0], b = f[1];
        out[0] = a.x; out[1] = a.y; out[2] = a.z; out[3] = a.w;
        out[4] = b.x; out[5] = b.y; out[6] = b.z; out[7] = b.w;
    } else {
        uint4 d = *(const uint4*)(p + idx);
        u16 v[8]; *(uint4*)v = d;
#pragma unroll
        for (int j = 0; j < 8; ++j) out[j] = bf2f(v[j]);
    }
}

// ---------------- dtype sniffer: low u16 of each word is a plausible bf16 only for bf16 data
__global__ __launch_bounds__(256)
void detect_dtype(const u16* __restrict__ x, int* __restrict__ flag) {
    __shared__ int sh[256];
    int t = threadIdx.x;
    const uint32_t* w = (const uint32_t*)x;
    int cnt = 0;
    for (int i = t; i < 4096; i += 256) {
        int e = (w[i] >> 7) & 0xFF;
        if (e >= 110 && e <= 134) cnt++;
    }
    sh[t] = cnt;
    __syncthreads();
    if (t == 0) {
        int s = 0;
        for (int i = 0; i < 256; ++i) s += sh[i];
        *flag = (s < 2048) ? 1 : 0;    // 1 => inputs are float32
    }
}

// ---------------- convert all parameter tensors to canonical bf16 in ws
struct WArgs {
    const void* src[17];
    int off[17];
    int n[17];
};
__global__ __launch_bounds__(256)
void convert_params(WArgs a, const int* __restrict__ flag, u16* __restrict__ dst) {
    int isf32 = *flag;
    int w = blockIdx.y;
    const void* s = a.src[w];
    u16* d = dst + a.off[w];
    int n = a.n[w];
    for (int i = blockIdx.x * 256 + threadIdx.x; i < n; i += gridDim.x * 256)
        d[i] = isf32 ? f2bf(((const float*)s)[i]) : ((const u16*)s)[i];
}

// ---------------- LN stats: per-pixel mean/rstd over 256 channels (NCHW input)
__global__ __launch_bounds__(256)
void ln_stats(const u16* __restrict__ x, const int* __restrict__ flag,
              float* __restrict__ mu, float* __restrict__ rstd) {
    int isf32 = *flag;
    int g = blockIdx.x * 256 + threadIdx.x;       // pixel id 0..131071
    int b = g >> 14, n = g & (NPIX - 1);
    float s = 0.f, s2 = 0.f;
    if (isf32) {
        const float* p = (const float*)x + (size_t)b * DIM * NPIX + n;
        for (int c = 0; c < DIM; ++c) { float v = p[(size_t)c * NPIX]; s += v; s2 += v * v; }
    } else {
        const u16* p = x + (size_t)b * DIM * NPIX + n;
        for (int c = 0; c < DIM; ++c) { float v = bf2f(p[(size_t)c * NPIX]); s += v; s2 += v * v; }
    }
    float m = s * (1.f / 256.f);
    float var = s2 * (1.f / 256.f) - m * m;
    mu[g] = m;
    rstd[g] = rsqrtf(var + 1e-5f);
}

// ---------------- LN + transpose NCHW -> NHWC (bf16 out)
__global__ __launch_bounds__(256)
void ln_transpose(const u16* __restrict__ x, const int* __restrict__ flag,
                  const float* __restrict__ mu, const float* __restrict__ rstd,
                  const u16* __restrict__ lnw, const u16* __restrict__ lnb,
                  u16* __restrict__ xt) {
    int isf32 = *flag;
    __shared__ u16 T[64][72];                     // [n_local][c_local], padded
    int b = blockIdx.x >> 8;
    int n0 = (blockIdx.x & 255) * 64;
    int c0 = blockIdx.y * 64;
    int t = threadIdx.x;
#pragma unroll
    for (int l = 0; l < 2; ++l) {
        int idx = t + l * 256;
        int cl = idx >> 3, nch = (idx & 7) * 8;
        float vals[8];
        load8(x, ((size_t)(b * DIM + c0 + cl)) * NPIX + n0 + nch, isf32, vals);
        float w = bf2f(lnw[c0 + cl]), bb = bf2f(lnb[c0 + cl]);
#pragma unroll
        for (int j = 0; j < 8; ++j) {
            int g = b * NPIX + n0 + nch + j;
            float v = (vals[j] - mu[g]) * rstd[g] * w + bb;
            T[nch + j][cl] = f2bf(v);
        }
    }
    __syncthreads();
#pragma unroll
    for (int l = 0; l < 2; ++l) {
        int idx = t + l * 256;
        int nl = idx >> 3, cch = (idx & 7) * 8;
        uint4 d = *(const uint4*)&T[nl][cch];
        *(uint4*)(xt + (size_t)(b * NPIX + n0 + nl) * DIM + c0 + cch) = d;
    }
}

// ---------------- GEMM: C[M][ldc] = A[M][256] @ Bw[Nout][256]^T + bias (+addt)
template <int HAS_ADD>
__global__ __launch_bounds__(256)
void gemm_bf16(const u16* __restrict__ A, const u16* __restrict__ Bw,
               const u16* __restrict__ bias, const u16* __restrict__ addt,
               u16* __restrict__ C, int ldc) {
    __shared__ u16 As[128][40];
    __shared__ u16 Bs[128][40];
    const int m0 = blockIdx.x * 128;
    const int n0 = blockIdx.y * 128;
    const int t = threadIdx.x;
    const int lane = t & 63;
    const int wid = t >> 6;
    const int wm = (wid >> 1) * 64;
    const int wn = (wid & 1) * 64;
    const int frow = lane & 15;
    const int koff = (lane >> 4) * 8;
    floatx4 acc[4][4] = {};
    for (int k0 = 0; k0 < 256; k0 += 32) {
#pragma unroll
        for (int l = 0; l < 2; ++l) {
            int idx = t + l * 256;
            int r = idx >> 2, ch = (idx & 3) * 8;
            *(uint4*)&As[r][ch] = *(const uint4*)(A + (size_t)(m0 + r) * 256 + k0 + ch);
            *(uint4*)&Bs[r][ch] = *(const uint4*)(Bw + (size_t)(n0 + r) * 256 + k0 + ch);
        }
        __syncthreads();
        short8 af[4], bfr[4];
#pragma unroll
        for (int i = 0; i < 4; ++i) {
            af[i] = *(const short8*)&As[wm + i * 16 + frow][koff];
            bfr[i] = *(const short8*)&Bs[wn + i * 16 + frow][koff];
        }
#pragma unroll
        for (int i = 0; i < 4; ++i)
#pragma unroll
            for (int j = 0; j < 4; ++j)
                acc[i][j] = __builtin_amdgcn_mfma_f32_16x16x32_bf16(af[i], bfr[j], acc[i][j], 0, 0, 0);
        __syncthreads();
    }
    const int col = lane & 15;
    const int r0 = (lane >> 4) * 4;
#pragma unroll
    for (int j = 0; j < 4; ++j) {
        int o = n0 + wn + j * 16 + col;
        float bv = bf2f(bias[o]);
#pragma unroll
        for (int i = 0; i < 4; ++i) {
#pragma unroll
            for (int r = 0; r < 4; ++r) {
                int m = m0 + wm + i * 16 + r0 + r;
                size_t off = (size_t)m * ldc + o;
                float v = acc[i][j][r] + bv;
                if (HAS_ADD) v += bf2f(addt[off]);
                C[off] = f2bf(v);
            }
        }
    }
}

// ---------------- depthwise 3x3 SAME, NHWC, register weights, 4 x-pixels/thread
template <int C, int HAS_BIAS, int DO_GELU>
__global__ __launch_bounds__(256)
void dwconv3_reg(const u16* __restrict__ in, int in_stride, int in_off,
                 const u16* __restrict__ w9, const u16* __restrict__ bias,
                 u16* __restrict__ out, int out_stride, int out_off) {
    constexpr int TPP = C / 8;              // threads per 4-pixel group
    constexpr int GRP = 256 / TPP;          // groups per block
    constexpr int XSEG = 128 / (GRP * 4);   // blocks per row
    int t = threadIdx.x;
    int cl = t & (TPP - 1);
    int g = t / TPP;
    int c8 = cl * 8;
    int blk = blockIdx.x;
    int xs = blk & (XSEG - 1);
    int tmp = blk / XSEG;
    int y = tmp & 127;
    int b = tmp >> 7;
    int x0 = xs * (GRP * 4) + g * 4;

    // per-thread weights: 72 contiguous u16 at w9 + c8*9 (16B-aligned)
    u16 wl[72];
#pragma unroll
    for (int i = 0; i < 9; ++i)
        *((uint4*)wl + i) = *((const uint4*)(w9 + c8 * 9) + i);
    float wgt[9][8];
#pragma unroll
    for (int tap = 0; tap < 9; ++tap)
#pragma unroll
        for (int j = 0; j < 8; ++j)
            wgt[tap][j] = bf2f(wl[j * 9 + tap]);

    float acc[4][8] = {};
#pragma unroll
    for (int dy = -1; dy <= 1; ++dy) {
        int yy = y + dy;
        if ((unsigned)yy >= 128u) continue;            // block-uniform branch
        const u16* rp = in + (size_t)(b * NPIX + yy * 128) * in_stride + in_off + c8;
#pragma unroll
        for (int ci = 0; ci < 6; ++ci) {
            int cc = x0 - 1 + ci;
            if ((unsigned)cc >= 128u) continue;        // edge threads only
            uint4 d = *(const uint4*)(rp + (size_t)cc * in_stride);
            u16 v[8]; *(uint4*)v = d;
            float fv[8];
#pragma unroll
            for (int j = 0; j < 8; ++j) fv[j] = bf2f(v[j]);
#pragma unroll
            for (int dx = -1; dx <= 1; ++dx) {
                int p = ci - 1 - dx;                   // compile-time
                if (p < 0 || p > 3) continue;
                int tap = (dy + 1) * 3 + (dx + 1);
#pragma unroll
                for (int j = 0; j < 8; ++j) acc[p][j] += fv[j] * wgt[tap][j];
            }
        }
    }

    float bi[8];
    if (HAS_BIAS) {
        uint4 bd = *(const uint4*)(bias + c8);
        u16 bv[8]; *(uint4*)bv = bd;
#pragma unroll
        for (int j = 0; j < 8; ++j) bi[j] = bf2f(bv[j]);
    }
    u16* op = out + (size_t)(b * NPIX + y * 128 + x0) * out_stride + out_off + c8;
#pragma unroll
    for (int p = 0; p < 4; ++p) {
        u16 o[8];
#pragma unroll
        for (int j = 0; j < 8; ++j) {
            float r = acc[p][j];
            if (HAS_BIAS) r += bi[j];
            if (DO_GELU) r = gelu_fast(r);
            o[j] = f2bf(r);
        }
        *(uint4*)(op + (size_t)p * out_stride) = *(uint4*)o;
    }
}

__global__ __launch_bounds__(256)
void finalize_scales(const float* __restrict__ qss, const float* __restrict__ kss,
                     float* __restrict__ qsc, float* __restrict__ ksc) {
    int i = blockIdx.x * 256 + threadIdx.x;        // 2048
    qsc[i] = 1.f / fmaxf(sqrtf(qss[i]), 1e-12f);
    ksc[i] = 1.f / fmaxf(sqrtf(kss[i]), 1e-12f);
}

// ---------------- Gram: partial[blk][h,i,j] = sum_{n in chunk} q[n][h*32+i] * k[n][h*32+j]
// Fused: also accumulates per-channel sum-of-squares of q and k (replaces colsumsq).
__global__ __launch_bounds__(256)
void gram_kernel(const u16* __restrict__ qT, const u16* __restrict__ kvT,
                 float* __restrict__ Gpart, float* __restrict__ qss,
                 float* __restrict__ kss) {
    int blk = blockIdx.x;                          // 8 b * 128 chunks
    int b = blk >> 7, chunk = blk & 127;
    int t = threadIdx.x;                           // channel; h = t>>5, i = t&31
    int hbase = t & 0xE0;                          // h*32
    int row0 = b * NPIX + chunk * 128;
    const u16* qp = qT + (size_t)row0 * 256 + t;
    const u16* kp = kvT + (size_t)row0 * 512;      // k at column offset 0
    float acc[32];
#pragma unroll
    for (int j = 0; j < 32; ++j) acc[j] = 0.f;
    float qs2 = 0.f, ks2 = 0.f;
#pragma unroll 2
    for (int r = 0; r < 128; ++r) {
        float qv = bf2f(qp[(size_t)r * 256]);
        const u16* krow = kp + (size_t)r * 512;
        float kt = bf2f(krow[t]);
        qs2 += qv * qv;
        ks2 += kt * kt;
        uint4 k0 = *(const uint4*)(krow + hbase);
        uint4 k1 = *(const uint4*)(krow + hbase + 8);
        uint4 k2 = *(const uint4*)(krow + hbase + 16);
        uint4 k3 = *(const uint4*)(krow + hbase + 24);
        u16 kv16[32];
        *(uint4*)(kv16 + 0)  = k0;
        *(uint4*)(kv16 + 8)  = k1;
        *(uint4*)(kv16 + 16) = k2;
        *(uint4*)(kv16 + 24) = k3;
#pragma unroll
        for (int j = 0; j < 32; ++j) acc[j] += qv * bf2f(kv16[j]);
    }
    float* gp = Gpart + (size_t)blk * 8192 + t * 32;
#pragma unroll
    for (int j = 0; j < 32; j += 4)
        *(float4*)(gp + j) = make_float4(acc[j], acc[j + 1], acc[j + 2], acc[j + 3]);
    atomicAdd(&qss[b * 256 + t], qs2);
    atomicAdd(&kss[b * 256 + t], ks2);
}

// ---------------- reduce 128 gram partials, apply scales + temperature, softmax over j
__global__ __launch_bounds__(1024)
void softmax32(const float* __restrict__ Gpart, const float* __restrict__ qsc,
               const float* __restrict__ ksc, const u16* __restrict__ temp,
               float* __restrict__ attn) {
    int bh = blockIdx.x;
    int b = bh >> 3, h = bh & 7;
    int t = threadIdx.x;
    int i = t >> 5, j = t & 31;
    const float* gp = Gpart + (size_t)b * 128 * 8192 + (size_t)((h * 32 + i) * 32 + j);
    float s0 = 0.f, s1 = 0.f, s2 = 0.f, s3 = 0.f;
    for (int p = 0; p < 128; p += 4) {
        s0 += gp[(size_t)p * 8192];
        s1 += gp[(size_t)(p + 1) * 8192];
        s2 += gp[(size_t)(p + 2) * 8192];
        s3 += gp[(size_t)(p + 3) * 8192];
    }
    float qs = qsc[b * 256 + h * 32 + i];
    float ks = ksc[b * 256 + h * 32 + j];
    float tm = bf2f(temp[h]);
    float v = ((s0 + s1) + (s2 + s3)) * qs * ks * tm;
    float m = v;
    for (int s = 16; s; s >>= 1) m = fmaxf(m, __shfl_xor(m, s, 32));
    float e = __expf(v - m);
    float sum = e;
    for (int s = 16; s; s >>= 1) sum += __shfl_xor(sum, s, 32);
    attn[((size_t)(b * 8 + h) * 32 + i) * 32 + j] = e / sum;
}

// ---------------- out[n][c] = sum_j attn[h,i,j] * v[n][h*32+j]  (channels-last out)
// Sync-free, LDS-free (gram-style): thread t owns channel t; its 32 attn weights
// sit in VGPRs; V rows are half-wave-identical uint4 broadcasts merged by the
// coalescer. 2048 blocks x 64 rows for short serial tails.
__global__ __launch_bounds__(256)
void attnv_kernel(const float* __restrict__ attn, const u16* __restrict__ kvT,
                  u16* __restrict__ outT) {
    int blk = blockIdx.x;                          // 8 b * 256 chunks of 64 rows
    int b = blk >> 8, chunk = blk & 255;
    int t = threadIdx.x;                           // output channel; h = t>>5
    int hbase = t & 0xE0;
    float at[32];
    const float4* ap = (const float4*)(attn + (size_t)b * 8192 + (size_t)t * 32);
#pragma unroll
    for (int j = 0; j < 8; ++j) {
        float4 d = ap[j];
        at[j * 4 + 0] = d.x; at[j * 4 + 1] = d.y;
        at[j * 4 + 2] = d.z; at[j * 4 + 3] = d.w;
    }
    int row0 = b * NPIX + chunk * 64;
    const u16* vp = kvT + (size_t)row0 * 512 + 256 + hbase;
    u16* op = outT + (size_t)row0 * 256 + t;
#pragma unroll 2
    for (int r = 0; r < 64; ++r) {
        const u16* vrow = vp + (size_t)r * 512;
        uint4 k0 = *(const uint4*)(vrow);
        uint4 k1 = *(const uint4*)(vrow + 8);
        uint4 k2 = *(const uint4*)(vrow + 16);
        uint4 k3 = *(const uint4*)(vrow + 24);
        u16 v16[32];
        *(uint4*)(v16 + 0)  = k0;
        *(uint4*)(v16 + 8)  = k1;
        *(uint4*)(v16 + 16) = k2;
        *(uint4*)(v16 + 24) = k3;
        float a = 0.f;
#pragma unroll
        for (int j = 0; j < 32; ++j) a += at[j] * bf2f(v16[j]);
        op[(size_t)r * 256] = f2bf(a);
    }
}

// ---------------- transpose NHWC Fp back to NCHW, add hx, write out (flag-aware format)
__global__ __launch_bounds__(256)
void final_out(const u16* __restrict__ Fp, const u16* __restrict__ hx,
               const int* __restrict__ flag, u16* __restrict__ out) {
    int isf32 = *flag;
    __shared__ u16 T[64][72];
    int b = blockIdx.x >> 8;
    int n0 = (blockIdx.x & 255) * 64;
    int c0 = blockIdx.y * 64;
    int t = threadIdx.x;
#pragma unroll
    for (int l = 0; l < 2; ++l) {
        int idx = t + l * 256;
        int nl = idx >> 3, cch = (idx & 7) * 8;
        *(uint4*)&T[nl][cch] = *(const uint4*)(Fp + (size_t)(b * NPIX + n0 + nl) * 256 + c0 + cch);
    }
    __syncthreads();
#pragma unroll
    for (int l = 0; l < 2; ++l) {
        int idx = t + l * 256;
        int cl = idx >> 3, nch = (idx & 7) * 8;
        size_t g = (size_t)(b * DIM + c0 + cl) * NPIX + n0 + nch;
        float hv[8];
        load8(hx, g, isf32, hv);
        float r[8];
#pragma unroll
        for (int j = 0; j < 8; ++j) r[j] = bf2f(T[nch + j][cl]) + hv[j];
        if (isf32) {
            float* o = (float*)out + g;
            *(float4*)o       = make_float4(r[0], r[1], r[2], r[3]);
            *(float4*)(o + 4) = make_float4(r[4], r[5], r[6], r[7]);
        } else {
            u16 ov[8];
#pragma unroll
            for (int j = 0; j < 8; ++j) ov[j] = f2bf(r[j]);
            *(uint4*)(out + g) = *(uint4*)ov;
        }
    }
}

__global__ void ws_marker(u16* out) {
    if (threadIdx.x < 64) ((uint32_t*)out)[threadIdx.x] = 0x46402400u;  // 12345.0f pattern
}

extern "C" void kernel_launch(void* const* d_in, const int* in_sizes, int n_in,
                              void* d_out, int out_size, void* d_ws, size_t ws_size,
                              hipStream_t stream) {
    const u16* x    = (const u16*)d_in[0];
    const u16* hx   = (const u16*)d_in[1];
    u16* outp = (u16*)d_out;

    char* ws = (char*)d_ws;
    float* F = (float*)ws;
    float* mu_x   = F;
    float* rstd_x = F + 131072;
    float* mu_h   = F + 262144;
    float* rstd_h = F + 393216;
    float* qss    = F + 524288;
    float* kss    = F + 526336;
    float* qsc    = F + 528384;
    float* ksc    = F + 530432;
    float* attn   = F + 598016;
    int*   dflag  = (int*)(F + 663552);
    u16*   W      = (u16*)(ws + 2752512);          // canonical bf16 params
    u16* R1 = (u16*)(ws + (((size_t)4)   << 20));   // 64 MiB
    u16* R2 = (u16*)(ws + (((size_t)68)  << 20));   // 64 MiB
    u16* R3 = (u16*)(ws + (((size_t)132) << 20));   // 128 MiB
    u16* R4 = (u16*)(ws + (((size_t)260) << 20));   // 128 MiB
    float* Gpart = (float*)R2;   // 32 MiB of gram partials; R2 is dead at gram time

    size_t need = ((size_t)388) << 20;
    if (ws_size < need) {
        ws_marker<<<1, 64, 0, stream>>>(outp);
        return;
    }

    // canonical param element offsets in W
    const int O_QW = 0, O_KVW = 65536, O_AOW = 196608, O_QB = 262144, O_KVB = 262400,
              O_AOB = 262912, O_LN1W = 263168, O_LN1B = 263424, O_LN2W = 263680,
              O_LN2B = 263936, O_QDWW = 264192, O_QDWB = 266496, O_KVDWW = 266752,
              O_KVDWB = 271360, O_PE1 = 271872, O_PE2 = 274176, O_TEMP = 276480;

    WArgs wa;
    const int srcidx[17] = {6, 10, 14, 7, 11, 15, 2, 3, 4, 5, 8, 9, 12, 13, 16, 17, 18};
    const int offs[17]   = {O_QW, O_KVW, O_AOW, O_QB, O_KVB, O_AOB, O_LN1W, O_LN1B,
                            O_LN2W, O_LN2B, O_QDWW, O_QDWB, O_KVDWW, O_KVDWB,
                            O_PE1, O_PE2, O_TEMP};
    const int ns[17]     = {65536, 131072, 65536, 256, 512, 256, 256, 256, 256, 256,
                            2304, 256, 4608, 512, 2304, 2304, 8};
    for (int i = 0; i < 17; ++i) { wa.src[i] = d_in[srcidx[i]]; wa.off[i] = offs[i]; wa.n[i] = ns[i]; }

    detect_dtype<<<1, 256, 0, stream>>>(x, dflag);
    convert_params<<<dim3(16, 17), 256, 0, stream>>>(wa, dflag, W);

    // zero sumsq accumulators (qss/kss/qsc/ksc region)
    hipMemsetAsync(ws + (size_t)524288 * 4, 0, (size_t)(532480 - 524288) * 4, stream);

    ln_stats<<<512, 256, 0, stream>>>(x, dflag, mu_x, rstd_x);
    ln_stats<<<512, 256, 0, stream>>>(hx, dflag, mu_h, rstd_h);

    ln_transpose<<<dim3(2048, 4), 256, 0, stream>>>(x, dflag, mu_x, rstd_x, W + O_LN1W, W + O_LN1B, R1);
    gemm_bf16<0><<<dim3(1024, 2), 256, 0, stream>>>(R1, W + O_QW, W + O_QB, nullptr, R2, 256);

    ln_transpose<<<dim3(2048, 4), 256, 0, stream>>>(hx, dflag, mu_h, rstd_h, W + O_LN2W, W + O_LN2B, R1);
    gemm_bf16<0><<<dim3(1024, 4), 256, 0, stream>>>(R1, W + O_KVW, W + O_KVB, nullptr, R3, 512);

    dwconv3_reg<256, 1, 0><<<4096, 256, 0, stream>>>(R2, 256, 0, W + O_QDWW, W + O_QDWB, R1, 256, 0);
    dwconv3_reg<512, 1, 0><<<8192, 256, 0, stream>>>(R3, 512, 0, W + O_KVDWW, W + O_KVDWB, R4, 512, 0);

    // fused gram + colsumsq: 1024 sync-free blocks, per-block partial G
    gram_kernel<<<1024, 256, 0, stream>>>(R1, R4, Gpart, qss, kss);
    finalize_scales<<<8, 256, 0, stream>>>(qss, kss, qsc, ksc);
    softmax32<<<64, 1024, 0, stream>>>(Gpart, qsc, ksc, W + O_TEMP, attn);
    attnv_kernel<<<2048, 256, 0, stream>>>(attn, R4, R2);

    dwconv3_reg<256, 0, 1><<<4096, 256, 0, stream>>>(R4, 512, 256, W + O_PE1, nullptr, R3, 256, 0);
    dwconv3_reg<256, 0, 0><<<4096, 256, 0, stream>>>(R3, 256, 0, W + O_PE2, nullptr, R1, 256, 0);

    gemm_bf16<1><<<dim3(1024, 2), 256, 0, stream>>>(R2, W + O_AOW, W + O_AOB, R1, R3, 256);
    final_out<<<dim3(2048, 4), 256, 0, stream>>>(R3, hx, dflag, outp);
}

// Round 4
// 1237.208 us; speedup vs baseline: 1.2852x; 1.0157x over previous
//
#include <hip/hip_runtime.h>
#include <cstdio>
#include <cstdint>

typedef unsigned short u16;
typedef short short8 __attribute__((ext_vector_type(8)));
typedef float floatx4 __attribute__((ext_vector_type(4)));

#define NPIX 16384      // 128*128
#define DIM 256

__device__ inline float bf2f(u16 v) {
    return __uint_as_float(((uint32_t)v) << 16);
}
__device__ inline u16 f2bf(float f) {
    uint32_t u = __float_as_uint(f);
    u += 0x7fffu + ((u >> 16) & 1u);
    return (u16)(u >> 16);
}
// gelu(x) = x * sigmoid(2*0.79788456*(x+0.044715x^3)) — exact rewrite of tanh form
__device__ inline float gelu_fast(float x) {
    float x3 = x * x * x;
    float z2 = 1.5957691216057308f * (x + 0.044715f * x3);   // 2*sqrt(2/pi)*(...)
    return x * __builtin_amdgcn_rcpf(1.f + __expf(-z2));
}
// flag-aware load of 8 consecutive elements from a raw input tensor
__device__ inline void load8(const u16* p, size_t idx, int isf32, float out[8]) {
    if (isf32) {
        const float4* f = (const float4*)((const float*)p + idx);
        float4 a = f[0], b = f[1];
        out[0] = a.x; out[1] = a.y; out[2] = a.z; out[3] = a.w;
        out[4] = b.x; out[5] = b.y; out[6] = b.z; out[7] = b.w;
    } else {
        uint4 d = *(const uint4*)(p + idx);
        u16 v[8]; *(uint4*)v = d;
#pragma unroll
        for (int j = 0; j < 8; ++j) out[j] = bf2f(v[j]);
    }
}

// ---------------- dtype sniffer: low u16 of each word is a plausible bf16 only for bf16 data
__global__ __launch_bounds__(256)
void detect_dtype(const u16* __restrict__ x, int* __restrict__ flag) {
    __shared__ int sh[256];
    int t = threadIdx.x;
    const uint32_t* w = (const uint32_t*)x;
    int cnt = 0;
    for (int i = t; i < 4096; i += 256) {
        int e = (w[i] >> 7) & 0xFF;
        if (e >= 110 && e <= 134) cnt++;
    }
    sh[t] = cnt;
    __syncthreads();
    if (t == 0) {
        int s = 0;
        for (int i = 0; i < 256; ++i) s += sh[i];
        *flag = (s < 2048) ? 1 : 0;    // 1 => inputs are float32
    }
}

// ---------------- convert all parameter tensors to canonical bf16 in ws
struct WArgs {
    const void* src[17];
    int off[17];
    int n[17];
};
__global__ __launch_bounds__(256)
void convert_params(WArgs a, const int* __restrict__ flag, u16* __restrict__ dst) {
    int isf32 = *flag;
    int w = blockIdx.y;
    const void* s = a.src[w];
    u16* d = dst + a.off[w];
    int n = a.n[w];
    for (int i = blockIdx.x * 256 + threadIdx.x; i < n; i += gridDim.x * 256)
        d[i] = isf32 ? f2bf(((const float*)s)[i]) : ((const u16*)s)[i];
}

// ---------------- fused LN: stats + normalize + transpose NCHW -> NHWC bf16.
// One global read of x (vs 2 in the split version). 32-pixel x 256-ch f32 tile
// in LDS (stride 257 words: stats read bank = (p+k)%32, 2-way = free).
__global__ __launch_bounds__(256)
void ln_fused(const u16* __restrict__ x, const int* __restrict__ flag,
              const u16* __restrict__ lnw, const u16* __restrict__ lnb,
              u16* __restrict__ xt) {
    int isf32 = *flag;
    __shared__ float T[32][257];
    __shared__ float wsh[256], bsh[256];
    __shared__ float2 red[8][32];
    __shared__ float2 mst[32];
    int t = threadIdx.x;
    int b = blockIdx.x >> 9;                      // 512 chunks of 32 pixels per batch
    int n0 = (blockIdx.x & 511) * 32;
    // stage raw f32 tile, coalesced (lanes cover contiguous pixel ranges per channel)
    if (isf32) {
        const float* xp = (const float*)x;
#pragma unroll
        for (int pass = 0; pass < 8; ++pass) {
            int c = (t >> 3) + pass * 32;
            int px = (t & 7) * 4;
            float4 d = *(const float4*)(xp + ((size_t)(b * 256 + c)) * NPIX + n0 + px);
            T[px][c] = d.x; T[px + 1][c] = d.y; T[px + 2][c] = d.z; T[px + 3][c] = d.w;
        }
    } else {
#pragma unroll
        for (int pass = 0; pass < 4; ++pass) {
            int c = (t >> 2) + pass * 64;
            int px = (t & 3) * 8;
            uint4 d = *(const uint4*)(x + ((size_t)(b * 256 + c)) * NPIX + n0 + px);
            u16 v[8]; *(uint4*)v = d;
#pragma unroll
            for (int j = 0; j < 8; ++j) T[px + j][c] = bf2f(v[j]);
        }
    }
    wsh[t] = bf2f(lnw[t]);
    bsh[t] = bf2f(lnb[t]);
    __syncthreads();
    // stats: thread (p = t&31, q = t>>5) sums channels q*32..q*32+31 of pixel p
    int p = t & 31, q = t >> 5;
    float s = 0.f, s2 = 0.f;
#pragma unroll
    for (int k = 0; k < 32; ++k) {
        float v = T[p][q * 32 + k];
        s += v; s2 += v * v;
    }
    red[q][p] = make_float2(s, s2);
    __syncthreads();
    if (t < 32) {
        float ss = 0.f, ss2 = 0.f;
#pragma unroll
        for (int qq = 0; qq < 8; ++qq) { ss += red[qq][t].x; ss2 += red[qq][t].y; }
        float m = ss * (1.f / 256.f);
        float var = ss2 * (1.f / 256.f) - m * m;
        mst[t] = make_float2(m, rsqrtf(var + 1e-5f));
    }
    __syncthreads();
    float2 ms = mst[p];
    u16 ov[32];
#pragma unroll
    for (int k = 0; k < 32; ++k) {
        int c = q * 32 + k;
        float v = (T[p][c] - ms.x) * ms.y * wsh[c] + bsh[c];
        ov[k] = f2bf(v);
    }
    u16* op = xt + ((size_t)(b * NPIX + n0 + p)) * 256 + q * 32;
#pragma unroll
    for (int k = 0; k < 32; k += 8)
        *(uint4*)(op + k) = *(uint4*)(ov + k);
}

// ---------------- GEMM: C[M][ldc] = A[M][256] @ Bw[Nout][256]^T + bias (+addt)
template <int HAS_ADD>
__global__ __launch_bounds__(256)
void gemm_bf16(const u16* __restrict__ A, const u16* __restrict__ Bw,
               const u16* __restrict__ bias, const u16* __restrict__ addt,
               u16* __restrict__ C, int ldc) {
    __shared__ u16 As[128][40];
    __shared__ u16 Bs[128][40];
    const int m0 = blockIdx.x * 128;
    const int n0 = blockIdx.y * 128;
    const int t = threadIdx.x;
    const int lane = t & 63;
    const int wid = t >> 6;
    const int wm = (wid >> 1) * 64;
    const int wn = (wid & 1) * 64;
    const int frow = lane & 15;
    const int koff = (lane >> 4) * 8;
    floatx4 acc[4][4] = {};
    for (int k0 = 0; k0 < 256; k0 += 32) {
#pragma unroll
        for (int l = 0; l < 2; ++l) {
            int idx = t + l * 256;
            int r = idx >> 2, ch = (idx & 3) * 8;
            *(uint4*)&As[r][ch] = *(const uint4*)(A + (size_t)(m0 + r) * 256 + k0 + ch);
            *(uint4*)&Bs[r][ch] = *(const uint4*)(Bw + (size_t)(n0 + r) * 256 + k0 + ch);
        }
        __syncthreads();
        short8 af[4], bfr[4];
#pragma unroll
        for (int i = 0; i < 4; ++i) {
            af[i] = *(const short8*)&As[wm + i * 16 + frow][koff];
            bfr[i] = *(const short8*)&Bs[wn + i * 16 + frow][koff];
        }
#pragma unroll
        for (int i = 0; i < 4; ++i)
#pragma unroll
            for (int j = 0; j < 4; ++j)
                acc[i][j] = __builtin_amdgcn_mfma_f32_16x16x32_bf16(af[i], bfr[j], acc[i][j], 0, 0, 0);
        __syncthreads();
    }
    const int col = lane & 15;
    const int r0 = (lane >> 4) * 4;
#pragma unroll
    for (int j = 0; j < 4; ++j) {
        int o = n0 + wn + j * 16 + col;
        float bv = bf2f(bias[o]);
#pragma unroll
        for (int i = 0; i < 4; ++i) {
#pragma unroll
            for (int r = 0; r < 4; ++r) {
                int m = m0 + wm + i * 16 + r0 + r;
                size_t off = (size_t)m * ldc + o;
                float v = acc[i][j][r] + bv;
                if (HAS_ADD) v += bf2f(addt[off]);
                C[off] = f2bf(v);
            }
        }
    }
}

// ---------------- depthwise 3x3 SAME, NHWC, register weights, 4 x-pixels/thread
template <int C, int HAS_BIAS, int DO_GELU>
__global__ __launch_bounds__(256)
void dwconv3_reg(const u16* __restrict__ in, int in_stride, int in_off,
                 const u16* __restrict__ w9, const u16* __restrict__ bias,
                 u16* __restrict__ out, int out_stride, int out_off) {
    constexpr int TPP = C / 8;              // threads per 4-pixel group
    constexpr int GRP = 256 / TPP;          // groups per block
    constexpr int XSEG = 128 / (GRP * 4);   // blocks per row
    int t = threadIdx.x;
    int cl = t & (TPP - 1);
    int g = t / TPP;
    int c8 = cl * 8;
    int blk = blockIdx.x;
    int xs = blk & (XSEG - 1);
    int tmp = blk / XSEG;
    int y = tmp & 127;
    int b = tmp >> 7;
    int x0 = xs * (GRP * 4) + g * 4;

    // per-thread weights: 72 contiguous u16 at w9 + c8*9 (16B-aligned)
    u16 wl[72];
#pragma unroll
    for (int i = 0; i < 9; ++i)
        *((uint4*)wl + i) = *((const uint4*)(w9 + c8 * 9) + i);
    float wgt[9][8];
#pragma unroll
    for (int tap = 0; tap < 9; ++tap)
#pragma unroll
        for (int j = 0; j < 8; ++j)
            wgt[tap][j] = bf2f(wl[j * 9 + tap]);

    float acc[4][8] = {};
#pragma unroll
    for (int dy = -1; dy <= 1; ++dy) {
        int yy = y + dy;
        if ((unsigned)yy >= 128u) continue;            // block-uniform branch
        const u16* rp = in + (size_t)(b * NPIX + yy * 128) * in_stride + in_off + c8;
#pragma unroll
        for (int ci = 0; ci < 6; ++ci) {
            int cc = x0 - 1 + ci;
            if ((unsigned)cc >= 128u) continue;        // edge threads only
            uint4 d = *(const uint4*)(rp + (size_t)cc * in_stride);
            u16 v[8]; *(uint4*)v = d;
            float fv[8];
#pragma unroll
            for (int j = 0; j < 8; ++j) fv[j] = bf2f(v[j]);
#pragma unroll
            for (int dx = -1; dx <= 1; ++dx) {
                int p = ci - 1 - dx;                   // compile-time
                if (p < 0 || p > 3) continue;
                int tap = (dy + 1) * 3 + (dx + 1);
#pragma unroll
                for (int j = 0; j < 8; ++j) acc[p][j] += fv[j] * wgt[tap][j];
            }
        }
    }

    float bi[8];
    if (HAS_BIAS) {
        uint4 bd = *(const uint4*)(bias + c8);
        u16 bv[8]; *(uint4*)bv = bd;
#pragma unroll
        for (int j = 0; j < 8; ++j) bi[j] = bf2f(bv[j]);
    }
    u16* op = out + (size_t)(b * NPIX + y * 128 + x0) * out_stride + out_off + c8;
#pragma unroll
    for (int p = 0; p < 4; ++p) {
        u16 o[8];
#pragma unroll
        for (int j = 0; j < 8; ++j) {
            float r = acc[p][j];
            if (HAS_BIAS) r += bi[j];
            if (DO_GELU) r = gelu_fast(r);
            o[j] = f2bf(r);
        }
        *(uint4*)(op + (size_t)p * out_stride) = *(uint4*)o;
    }
}

// ---------------- Gram: partial[blk][h,i,j] = sum_{n in chunk} q[n][h*32+i] * k[n][h*32+j]
// Fused: also accumulates per-channel sum-of-squares of q and k.
// 2048 blocks x 64 rows: 8192 waves = 8 waves/SIMD (VGPR=36 permits) for latency hiding.
__global__ __launch_bounds__(256)
void gram_kernel(const u16* __restrict__ qT, const u16* __restrict__ kvT,
                 float* __restrict__ Gpart, float* __restrict__ qss,
                 float* __restrict__ kss) {
    int blk = blockIdx.x;                          // 8 b * 256 chunks of 64 rows
    int b = blk >> 8, chunk = blk & 255;
    int t = threadIdx.x;                           // channel; h = t>>5, i = t&31
    int hbase = t & 0xE0;                          // h*32
    int row0 = b * NPIX + chunk * 64;
    const u16* qp = qT + (size_t)row0 * 256 + t;
    const u16* kp = kvT + (size_t)row0 * 512;      // k at column offset 0
    float acc[32];
#pragma unroll
    for (int j = 0; j < 32; ++j) acc[j] = 0.f;
    float qs2 = 0.f, ks2 = 0.f;
#pragma unroll 2
    for (int r = 0; r < 64; ++r) {
        float qv = bf2f(qp[(size_t)r * 256]);
        const u16* krow = kp + (size_t)r * 512;
        float kt = bf2f(krow[t]);
        qs2 += qv * qv;
        ks2 += kt * kt;
        uint4 k0 = *(const uint4*)(krow + hbase);
        uint4 k1 = *(const uint4*)(krow + hbase + 8);
        uint4 k2 = *(const uint4*)(krow + hbase + 16);
        uint4 k3 = *(const uint4*)(krow + hbase + 24);
        u16 kv16[32];
        *(uint4*)(kv16 + 0)  = k0;
        *(uint4*)(kv16 + 8)  = k1;
        *(uint4*)(kv16 + 16) = k2;
        *(uint4*)(kv16 + 24) = k3;
#pragma unroll
        for (int j = 0; j < 32; ++j) acc[j] += qv * bf2f(kv16[j]);
    }
    float* gp = Gpart + (size_t)blk * 8192 + t * 32;
#pragma unroll
    for (int j = 0; j < 32; j += 4)
        *(float4*)(gp + j) = make_float4(acc[j], acc[j + 1], acc[j + 2], acc[j + 3]);
    atomicAdd(&qss[b * 256 + t], qs2);
    atomicAdd(&kss[b * 256 + t], ks2);
}

// ---------------- reduce 256 gram partials, scales (inline rsqrt) + temperature, softmax
__global__ __launch_bounds__(1024)
void softmax32(const float* __restrict__ Gpart, const float* __restrict__ qss,
               const float* __restrict__ kss, const u16* __restrict__ temp,
               float* __restrict__ attn) {
    int bh = blockIdx.x;
    int b = bh >> 3, h = bh & 7;
    int t = threadIdx.x;
    int i = t >> 5, j = t & 31;
    const float* gp = Gpart + (size_t)b * 256 * 8192 + (size_t)((h * 32 + i) * 32 + j);
    float s0 = 0.f, s1 = 0.f, s2 = 0.f, s3 = 0.f;
    for (int p = 0; p < 256; p += 4) {
        s0 += gp[(size_t)p * 8192];
        s1 += gp[(size_t)(p + 1) * 8192];
        s2 += gp[(size_t)(p + 2) * 8192];
        s3 += gp[(size_t)(p + 3) * 8192];
    }
    float qs = 1.f / fmaxf(sqrtf(qss[b * 256 + h * 32 + i]), 1e-12f);
    float ks = 1.f / fmaxf(sqrtf(kss[b * 256 + h * 32 + j]), 1e-12f);
    float tm = bf2f(temp[h]);
    float v = ((s0 + s1) + (s2 + s3)) * qs * ks * tm;
    float m = v;
    for (int s = 16; s; s >>= 1) m = fmaxf(m, __shfl_xor(m, s, 32));
    float e = __expf(v - m);
    float sum = e;
    for (int s = 16; s; s >>= 1) sum += __shfl_xor(sum, s, 32);
    attn[((size_t)(b * 8 + h) * 32 + i) * 32 + j] = e / sum;
}

// ---------------- out[n][c] = sum_j attn[h,i,j] * v[n][h*32+j]  (channels-last out)
__global__ __launch_bounds__(256)
void attnv_kernel(const float* __restrict__ attn, const u16* __restrict__ kvT,
                  u16* __restrict__ outT) {
    int blk = blockIdx.x;                          // 8 b * 256 chunks of 64 rows
    int b = blk >> 8, chunk = blk & 255;
    int t = threadIdx.x;                           // output channel; h = t>>5
    int hbase = t & 0xE0;
    float at[32];
    const float4* ap = (const float4*)(attn + (size_t)b * 8192 + (size_t)t * 32);
#pragma unroll
    for (int j = 0; j < 8; ++j) {
        float4 d = ap[j];
        at[j * 4 + 0] = d.x; at[j * 4 + 1] = d.y;
        at[j * 4 + 2] = d.z; at[j * 4 + 3] = d.w;
    }
    int row0 = b * NPIX + chunk * 64;
    const u16* vp = kvT + (size_t)row0 * 512 + 256 + hbase;
    u16* op = outT + (size_t)row0 * 256 + t;
#pragma unroll 2
    for (int r = 0; r < 64; ++r) {
        const u16* vrow = vp + (size_t)r * 512;
        uint4 k0 = *(const uint4*)(vrow);
        uint4 k1 = *(const uint4*)(vrow + 8);
        uint4 k2 = *(const uint4*)(vrow + 16);
        uint4 k3 = *(const uint4*)(vrow + 24);
        u16 v16[32];
        *(uint4*)(v16 + 0)  = k0;
        *(uint4*)(v16 + 8)  = k1;
        *(uint4*)(v16 + 16) = k2;
        *(uint4*)(v16 + 24) = k3;
        float a = 0.f;
#pragma unroll
        for (int j = 0; j < 32; ++j) a += at[j] * bf2f(v16[j]);
        op[(size_t)r * 256] = f2bf(a);
    }
}

// ---------------- transpose NHWC Fp back to NCHW, add hx, write out (flag-aware format)
__global__ __launch_bounds__(256)
void final_out(const u16* __restrict__ Fp, const u16* __restrict__ hx,
               const int* __restrict__ flag, u16* __restrict__ out) {
    int isf32 = *flag;
    __shared__ u16 T[64][72];
    int b = blockIdx.x >> 8;
    int n0 = (blockIdx.x & 255) * 64;
    int c0 = blockIdx.y * 64;
    int t = threadIdx.x;
#pragma unroll
    for (int l = 0; l < 2; ++l) {
        int idx = t + l * 256;
        int nl = idx >> 3, cch = (idx & 7) * 8;
        *(uint4*)&T[nl][cch] = *(const uint4*)(Fp + (size_t)(b * NPIX + n0 + nl) * 256 + c0 + cch);
    }
    __syncthreads();
#pragma unroll
    for (int l = 0; l < 2; ++l) {
        int idx = t + l * 256;
        int cl = idx >> 3, nch = (idx & 7) * 8;
        size_t g = (size_t)(b * DIM + c0 + cl) * NPIX + n0 + nch;
        float hv[8];
        load8(hx, g, isf32, hv);
        float r[8];
#pragma unroll
        for (int j = 0; j < 8; ++j) r[j] = bf2f(T[nch + j][cl]) + hv[j];
        if (isf32) {
            float* o = (float*)out + g;
            *(float4*)o       = make_float4(r[0], r[1], r[2], r[3]);
            *(float4*)(o + 4) = make_float4(r[4], r[5], r[6], r[7]);
        } else {
            u16 ov[8];
#pragma unroll
            for (int j = 0; j < 8; ++j) ov[j] = f2bf(r[j]);
            *(uint4*)(out + g) = *(uint4*)ov;
        }
    }
}

__global__ void ws_marker(u16* out) {
    if (threadIdx.x < 64) ((uint32_t*)out)[threadIdx.x] = 0x46402400u;  // 12345.0f pattern
}

extern "C" void kernel_launch(void* const* d_in, const int* in_sizes, int n_in,
                              void* d_out, int out_size, void* d_ws, size_t ws_size,
                              hipStream_t stream) {
    const u16* x    = (const u16*)d_in[0];
    const u16* hx   = (const u16*)d_in[1];
    u16* outp = (u16*)d_out;

    char* ws = (char*)d_ws;
    float* F = (float*)ws;
    float* qss    = F + 524288;
    float* kss    = F + 526336;
    float* attn   = F + 598016;
    int*   dflag  = (int*)(F + 663552);
    u16*   W      = (u16*)(ws + 2752512);          // canonical bf16 params
    u16* R1 = (u16*)(ws + (((size_t)4)   << 20));   // 64 MiB
    u16* R2 = (u16*)(ws + (((size_t)68)  << 20));   // 64 MiB
    u16* R3 = (u16*)(ws + (((size_t)132) << 20));   // 128 MiB
    u16* R4 = (u16*)(ws + (((size_t)260) << 20));   // 128 MiB
    float* Gpart = (float*)R2;   // 64 MiB of gram partials; R2 is dead at gram time
                                 // (consumed by softmax before attnv rewrites R2)

    size_t need = ((size_t)388) << 20;
    if (ws_size < need) {
        ws_marker<<<1, 64, 0, stream>>>(outp);
        return;
    }

    // canonical param element offsets in W
    const int O_QW = 0, O_KVW = 65536, O_AOW = 196608, O_QB = 262144, O_KVB = 262400,
              O_AOB = 262912, O_LN1W = 263168, O_LN1B = 263424, O_LN2W = 263680,
              O_LN2B = 263936, O_QDWW = 264192, O_QDWB = 266496, O_KVDWW = 266752,
              O_KVDWB = 271360, O_PE1 = 271872, O_PE2 = 274176, O_TEMP = 276480;

    WArgs wa;
    const int srcidx[17] = {6, 10, 14, 7, 11, 15, 2, 3, 4, 5, 8, 9, 12, 13, 16, 17, 18};
    const int offs[17]   = {O_QW, O_KVW, O_AOW, O_QB, O_KVB, O_AOB, O_LN1W, O_LN1B,
                            O_LN2W, O_LN2B, O_QDWW, O_QDWB, O_KVDWW, O_KVDWB,
                            O_PE1, O_PE2, O_TEMP};
    const int ns[17]     = {65536, 131072, 65536, 256, 512, 256, 256, 256, 256, 256,
                            2304, 256, 4608, 512, 2304, 2304, 8};
    for (int i = 0; i < 17; ++i) { wa.src[i] = d_in[srcidx[i]]; wa.off[i] = offs[i]; wa.n[i] = ns[i]; }

    detect_dtype<<<1, 256, 0, stream>>>(x, dflag);
    convert_params<<<dim3(16, 17), 256, 0, stream>>>(wa, dflag, W);

    // zero qss/kss atomic accumulators
    hipMemsetAsync(ws + (size_t)524288 * 4, 0, (size_t)(528384 - 524288) * 4, stream);

    ln_fused<<<4096, 256, 0, stream>>>(x, dflag, W + O_LN1W, W + O_LN1B, R1);
    gemm_bf16<0><<<dim3(1024, 2), 256, 0, stream>>>(R1, W + O_QW, W + O_QB, nullptr, R2, 256);

    ln_fused<<<4096, 256, 0, stream>>>(hx, dflag, W + O_LN2W, W + O_LN2B, R1);
    gemm_bf16<0><<<dim3(1024, 4), 256, 0, stream>>>(R1, W + O_KVW, W + O_KVB, nullptr, R3, 512);

    dwconv3_reg<256, 1, 0><<<4096, 256, 0, stream>>>(R2, 256, 0, W + O_QDWW, W + O_QDWB, R1, 256, 0);
    dwconv3_reg<512, 1, 0><<<8192, 256, 0, stream>>>(R3, 512, 0, W + O_KVDWW, W + O_KVDWB, R4, 512, 0);

    // fused gram + colsumsq: 2048 sync-free blocks (8 waves/SIMD), per-block partial G
    gram_kernel<<<2048, 256, 0, stream>>>(R1, R4, Gpart, qss, kss);
    softmax32<<<64, 1024, 0, stream>>>(Gpart, qss, kss, W + O_TEMP, attn);
    attnv_kernel<<<2048, 256, 0, stream>>>(attn, R4, R2);

    dwconv3_reg<256, 0, 1><<<4096, 256, 0, stream>>>(R4, 512, 256, W + O_PE1, nullptr, R3, 256, 0);
    dwconv3_reg<256, 0, 0><<<4096, 256, 0, stream>>>(R3, 256, 0, W + O_PE2, nullptr, R1, 256, 0);

    gemm_bf16<1><<<dim3(1024, 2), 256, 0, stream>>>(R2, W + O_AOW, W + O_AOB, R1, R3, 256);
    final_out<<<dim3(2048, 4), 256, 0, stream>>>(R3, hx, dflag, outp);
}